// Round 5
// baseline (192.983 us; speedup 1.0000x reference)
//
#include <hip/hip_runtime.h>

// x: (16, 128, 256, 256) f32 ; out: (16, 128, 128, 128) f32
// out = sum(v * sp(v)) / sum(sp(v)) over each non-overlapping 2x2 patch,
// sp(v) = v > 10 ? v : log(1 + exp(v))   (softplus with threshold=10)

#define H 256
#define W 256
#define HO 128
#define WO 128

typedef float fx4 __attribute__((ext_vector_type(4)));

__device__ __forceinline__ float sp_thresh(float v) {
    // softplus with threshold 10; exp(v<=10) <= 22026, no overflow
    return v > 10.0f ? v : __logf(1.0f + __expf(v));
}

struct f2 { float a, b; };

__device__ __forceinline__ f2 pool4(fx4 t, fx4 u) {
    // patch 0: {t[0], t[1], u[0], u[1]} ; patch 1: {t[2], t[3], u[2], u[3]}
    float s0 = sp_thresh(t[0]), s1 = sp_thresh(t[1]);
    float s2 = sp_thresh(u[0]), s3 = sp_thresh(u[1]);
    float num0 = t[0] * s0 + t[1] * s1 + u[0] * s2 + u[1] * s3;
    float den0 = s0 + s1 + s2 + s3;
    float s4 = sp_thresh(t[2]), s5 = sp_thresh(t[3]);
    float s6 = sp_thresh(u[2]), s7 = sp_thresh(u[3]);
    float num1 = t[2] * s4 + t[3] * s5 + u[2] * s6 + u[3] * s7;
    float den1 = s4 + s5 + s6 + s7;
    // den >= 4*softplus-min > 0; rcp is ~1ulp, threshold is 8.9e-2 -> fine
    f2 r;
    r.a = num0 * __builtin_amdgcn_rcpf(den0);
    r.b = num1 * __builtin_amdgcn_rcpf(den1);
    return r;
}

__global__ __launch_bounds__(256) void softpool2x2_kernel(
        const float* __restrict__ x, float* __restrict__ out) {
    int idx = blockIdx.x * blockDim.x + threadIdx.x;

    // each thread computes 8 adjacent output pixels:
    // input span = 16 cols x 2 rows = 64 B contiguous per row, 128 B total
    int w8   = idx & (WO / 8 - 1);        // oct index along output width: 0..15
    int rest = idx >> 4;
    int ho   = rest & (HO - 1);           // 0..127
    int bc   = rest >> 7;                 // b*c plane: 0..2047

    const fx4* r0 = reinterpret_cast<const fx4*>(
        x + (size_t)bc * (H * W) + (size_t)(2 * ho) * W + w8 * 16);
    const fx4* r1 = reinterpret_cast<const fx4*>(
        reinterpret_cast<const float*>(r0) + W);

    // streaming reads: input is touched exactly once, bypass cache allocation
    fx4 t0 = __builtin_nontemporal_load(r0);
    fx4 t1 = __builtin_nontemporal_load(r0 + 1);
    fx4 t2 = __builtin_nontemporal_load(r0 + 2);
    fx4 t3 = __builtin_nontemporal_load(r0 + 3);
    fx4 u0 = __builtin_nontemporal_load(r1);
    fx4 u1 = __builtin_nontemporal_load(r1 + 1);
    fx4 u2 = __builtin_nontemporal_load(r1 + 2);
    fx4 u3 = __builtin_nontemporal_load(r1 + 3);

    f2 p0 = pool4(t0, u0);
    f2 p1 = pool4(t1, u1);
    f2 p2 = pool4(t2, u2);
    f2 p3 = pool4(t3, u3);

    fx4 oa, ob;
    oa[0] = p0.a; oa[1] = p0.b; oa[2] = p1.a; oa[3] = p1.b;
    ob[0] = p2.a; ob[1] = p2.b; ob[2] = p3.a; ob[3] = p3.b;

    fx4* optr = reinterpret_cast<fx4*>(
        out + (size_t)bc * (HO * WO) + (size_t)ho * WO + w8 * 8);
    __builtin_nontemporal_store(oa, optr);
    __builtin_nontemporal_store(ob, optr + 1);
}

extern "C" void kernel_launch(void* const* d_in, const int* in_sizes, int n_in,
                              void* d_out, int out_size, void* d_ws, size_t ws_size,
                              hipStream_t stream) {
    const float* x = (const float*)d_in[0];
    float* out = (float*)d_out;
    // total threads: out_size / 8 = 16*128*128*16 = 4,194,304
    int nthreads = out_size / 8;
    int block = 256;
    int grid = nthreads / block;   // 16384, exact
    softpool2x2_kernel<<<grid, block, 0, stream>>>(x, out);
}

// Round 6
// 108.609 us; speedup vs baseline: 1.7769x; 1.7769x over previous
//
#include <hip/hip_runtime.h>

// x: (16, 128, 256, 256) f32 ; out: (16, 128, 128, 128) f32
// out = sum(v * sp(v)) / sum(sp(v)) over each non-overlapping 2x2 patch,
// sp(v) = v > 10 ? v : log(1 + exp(v))   (softplus with threshold=10)

#define H 256
#define W 256
#define HO 128
#define WO 128

typedef float fx4 __attribute__((ext_vector_type(4)));
typedef float fx2 __attribute__((ext_vector_type(2)));

__device__ __forceinline__ float sp_thresh(float v) {
    // softplus with threshold 10; exp(v<=10) <= 22026, no overflow
    return v > 10.0f ? v : __logf(1.0f + __expf(v));
}

__global__ __launch_bounds__(256) void softpool2x2_kernel(
        const float* __restrict__ x, float* __restrict__ out) {
    int idx = blockIdx.x * blockDim.x + threadIdx.x;

    // each thread computes 2 adjacent output pixels (4-col x 2-row input patch)
    // lane i <-> contiguous 16B: every load instruction is a dense
    // 1 KiB/wave span (perfect coalescing), every store a dense 512 B span.
    int wp   = idx & (WO / 2 - 1);        // pair index along output width: 0..63
    int rest = idx >> 6;
    int ho   = rest & (HO - 1);           // 0..127
    int bc   = rest >> 7;                 // b*c plane: 0..2047

    const float* base = x + (size_t)bc * (H * W) + (size_t)(2 * ho) * W + wp * 4;
    // streaming reads: input touched exactly once, bypass cache allocation
    fx4 t = __builtin_nontemporal_load(reinterpret_cast<const fx4*>(base));
    fx4 u = __builtin_nontemporal_load(reinterpret_cast<const fx4*>(base + W));

    // patch 0: {t[0], t[1], u[0], u[1]} ; patch 1: {t[2], t[3], u[2], u[3]}
    float s0 = sp_thresh(t[0]), s1 = sp_thresh(t[1]);
    float s2 = sp_thresh(u[0]), s3 = sp_thresh(u[1]);
    float num0 = t[0] * s0 + t[1] * s1 + u[0] * s2 + u[1] * s3;
    float den0 = s0 + s1 + s2 + s3;

    float s4 = sp_thresh(t[2]), s5 = sp_thresh(t[3]);
    float s6 = sp_thresh(u[2]), s7 = sp_thresh(u[3]);
    float num1 = t[2] * s4 + t[3] * s5 + u[2] * s6 + u[3] * s7;
    float den1 = s4 + s5 + s6 + s7;

    // den > 0 always (softplus > 0); rcp ~1ulp vs 8.9e-2 threshold -> fine
    fx2 o;
    o[0] = num0 * __builtin_amdgcn_rcpf(den0);
    o[1] = num1 * __builtin_amdgcn_rcpf(den1);

    float* optr = out + (size_t)bc * (HO * WO) + (size_t)ho * WO + wp * 2;
    __builtin_nontemporal_store(o, reinterpret_cast<fx2*>(optr));
}

extern "C" void kernel_launch(void* const* d_in, const int* in_sizes, int n_in,
                              void* d_out, int out_size, void* d_ws, size_t ws_size,
                              hipStream_t stream) {
    const float* x = (const float*)d_in[0];
    float* out = (float*)d_out;
    // total output pairs: 16*128*128*64 = 16,777,216
    int npairs = out_size / 2;
    int block = 256;
    int grid = npairs / block;   // 65536, exact
    softpool2x2_kernel<<<grid, block, 0, stream>>>(x, out);
}